// Round 18
// baseline (212.175 us; speedup 1.0000x reference)
//
#include <hip/hip_runtime.h>
#include <hip/hip_bf16.h>

// M=2 branches, K=3 diffusion, N=64, I=1, H=64, B=8, T=12

typedef __attribute__((ext_vector_type(8))) short short8;   // 8 bf16 (4 VGPRs)
typedef __attribute__((ext_vector_type(4))) float f32x4;    // 4 fp32

__device__ __forceinline__ short bf16_cvt(float f) {       // RNE, 1-2 ops
    __hip_bfloat16 h = __float2bfloat16(f);
    return __builtin_bit_cast(short, h);
}
__device__ __forceinline__ float bf16_tof(short s) {
    union { unsigned u; float f; } v; v.u = ((unsigned)s) << 16;
    return v.f;
}

// ---------------- prep: pack W, G^T, Whh into MFMA fragment order ----------
// Wf [layer][br][d][ht][kk][lane][8] : 147456/plane
// Gf [br][et][kk][lane][8]           : 24576/plane
// Whf[br][kt][gg][w][lane][8]        : 32768/plane  (B[k][gate] of WhhT)
__global__ __launch_bounds__(256) void k_prep(
    const float* __restrict__ G, const float* __restrict__ W0,
    const float* __restrict__ W1, const float* __restrict__ whh,
    short* __restrict__ Wfhi, short* __restrict__ Wflo,
    short* __restrict__ Gfhi, short* __restrict__ Gflo,
    short* __restrict__ Whfhi, short* __restrict__ Whflo)
{
    int idx = blockIdx.x * 256 + threadIdx.x;
    float v; short *dh, *dl; int didx;
    if (idx < 147456) {
        int j = idx & 7, lane = (idx >> 3) & 63, kk = (idx >> 9) % 6;
        int t2 = idx / 3072;
        int ht = t2 & 3; t2 >>= 2;
        int d = t2 % 3; t2 /= 3;
        int br = t2 & 1, layer = t2 >> 1;
        int k = kk * 32 + ((lane >> 4) << 3) + j;
        int o = k >> 6, l = k & 63, h = ht * 16 + (lane & 15);
        const float* Wp = layer ? W1 : W0;
        v = Wp[((size_t)br * 576 + (o * 3 + d) * 64 + l) * 64 + h];
        dh = Wfhi; dl = Wflo; didx = idx;
    } else if (idx < 172032) {
        int i2 = idx - 147456;
        int j = i2 & 7, lane = (i2 >> 3) & 63, kk = (i2 >> 9) % 6;
        int t2 = i2 / 3072;
        int et = t2 & 3, br = t2 >> 2;
        int k = kk * 32 + ((lane >> 4) << 3) + j;
        int d = k >> 6, c = k & 63, e = et * 16 + (lane & 15);
        v = G[(((size_t)br * 3 + d) * 64 + c) * 64 + e];
        dh = Gfhi; dl = Gflo; didx = i2;
    } else {
        int i3 = idx - 172032;
        int j = i3 & 7, lane = (i3 >> 3) & 63;
        int w = (i3 >> 9) & 3, gg = (i3 >> 11) & 3;
        int kt = (i3 >> 13) & 1, br = (i3 >> 14) & 1;
        int gate = gg * 64 + w * 16 + (lane & 15);
        int k = kt * 32 + ((lane >> 4) << 3) + j;
        v = whh[((size_t)br * 256 + gate) * 64 + k];
        dh = Whfhi; dl = Whflo; didx = i3;
    }
    short hi = bf16_cvt(v);
    dh[didx] = hi;
    dl[didx] = bf16_cvt(v - bf16_tof(hi));
}

// ---------------- LSTM v4.3: register weights, x prefetch, (256,3) ---------
// f32 X output. Plateaued at ~97.5 us, VALU+Mfma ~98% issue-saturated.
__global__ __launch_bounds__(256, 3) void k_lstm(
    const float* __restrict__ x, const short* __restrict__ Whfhi,
    const short* __restrict__ Whflo, const float* __restrict__ wih,
    const float* __restrict__ bih, const float* __restrict__ bhh,
    float* __restrict__ Xout)
{
    __shared__ short hbuf[2][2][16][64];   // [dbuf][plane][seq][hid^swz] 8 KB
    const int tid = threadIdx.x;
    const int lane = tid & 63;
    const int w = __builtin_amdgcn_readfirstlane(tid >> 6);   // gate slice 0..3
    const int q = lane >> 4, r16 = lane & 15;
    const int br = blockIdx.y;
    const int bx = blockIdx.x;
    const int dg = bx & 3, o = (bx >> 2) & 63, b = bx >> 8;

    // weight-stationary B fragments (hi/lo), statically indexed -> registers
    short8 Bh[2][4], Bl[2][4];
    {
        const short* wbh = Whfhi + (size_t)br * 16384;
        const short* wbl = Whflo + (size_t)br * 16384;
#pragma unroll
        for (int kt = 0; kt < 2; ++kt)
#pragma unroll
            for (int gg = 0; gg < 4; ++gg) {
                const int bidx = (((kt * 4 + gg) * 4 + w) * 64 + lane) * 8;
                Bh[kt][gg] = *(const short8*)(wbh + bidx);
                Bl[kt][gg] = *(const short8*)(wbl + bidx);
            }
    }

    float wihv[4], biasv[4];
#pragma unroll
    for (int gg = 0; gg < 4; ++gg) {
        const int gate = gg * 64 + w * 16 + r16;
        wihv[gg] = wih[br * 256 + gate];
        biasv[gg] = bih[br * 256 + gate] + bhh[br * 256 + gate];
    }

    float cst[4] = {0.f, 0.f, 0.f, 0.f};
    const float* xb = x + (size_t)b * 12 * 4096 + o * 64 + dg * 16;
    const size_t hob = ((size_t)(br * 8 + b) * 64 + o) * 4096 + dg * 1024;
    const int hid = w * 16 + r16;

    const float L2E = 1.442695041f, L2E2 = 2.885390082f;

    float4 nx = *(const float4*)(xb + q * 4);   // prefetch t=0

    for (int t = 0; t < 12; ++t) {
        float4 xv = nx;
        if (t < 11)   // issue next step's x early; hides under MFMA+acts
            nx = *(const float4*)(xb + (size_t)(t + 1) * 4096 + q * 4);
        float xm[4] = {xv.x, xv.y, xv.z, xv.w};
        f32x4 acc[4];   // [gg]
#pragma unroll
        for (int r = 0; r < 4; ++r)
#pragma unroll
            for (int gg = 0; gg < 4; ++gg)
                acc[gg][r] = fmaf(xm[r], wihv[gg], biasv[gg]);

        if (t > 0) {
            const short* hb0 = &hbuf[t & 1][0][0][0];
#pragma unroll
            for (int kt = 0; kt < 2; ++kt) {
                const int col = (kt * 32 + q * 8) ^ ((r16 & 7) << 3);
                short8 Ah = *(const short8*)&hb0[r16 * 64 + col];
                short8 Al = *(const short8*)&hb0[1024 + r16 * 64 + col];
#pragma unroll
                for (int gg = 0; gg < 4; ++gg) {
                    acc[gg] = __builtin_amdgcn_mfma_f32_16x16x32_bf16(
                        Ah, Bh[kt][gg], acc[gg], 0, 0, 0);
                    acc[gg] = __builtin_amdgcn_mfma_f32_16x16x32_bf16(
                        Ah, Bl[kt][gg], acc[gg], 0, 0, 0);
                    acc[gg] = __builtin_amdgcn_mfma_f32_16x16x32_bf16(
                        Al, Bh[kt][gg], acc[gg], 0, 0, 0);
                }
            }
        }
        // activations, torch order i,f,g,o. Fused products share one rcp.
        float hv_[4];
#pragma unroll
        for (int r = 0; r < 4; ++r) {
            float ei = __builtin_amdgcn_exp2f(acc[0][r] * -L2E);
            float Eg = __builtin_amdgcn_exp2f(acc[2][r] * L2E2);
            float ef = __builtin_amdgcn_exp2f(acc[1][r] * -L2E);
            float igt = (Eg - 1.f) *
                        __builtin_amdgcn_rcpf((1.f + ei) * (Eg + 1.f));
            float fg = __builtin_amdgcn_rcpf(1.f + ef);
            float c = fmaf(fg, cst[r], igt);
            cst[r] = c;
            float eo = __builtin_amdgcn_exp2f(acc[3][r] * -L2E);
            float Ec = __builtin_amdgcn_exp2f(c * L2E2);
            hv_[r] = (Ec - 1.f) *
                     __builtin_amdgcn_rcpf((1.f + eo) * (Ec + 1.f));
        }
        if (t == 11) {
#pragma unroll
            for (int r = 0; r < 4; ++r) {
                int seq = q * 4 + r;
                Xout[hob + seq * 64 + hid] = hv_[r];
            }
        } else {
            short* hw0 = &hbuf[(t + 1) & 1][0][0][0];
#pragma unroll
            for (int r = 0; r < 4; ++r) {
                int seq = q * 4 + r;
                int col = hid ^ ((seq & 7) << 3);
                short hi = bf16_cvt(hv_[r]);
                hw0[seq * 64 + col] = hi;
                hw0[1024 + seq * 64 + col] = bf16_cvt(hv_[r] - bf16_tof(hi));
            }
            __syncthreads();   // single barrier per step (dbuf)
        }
    }
}

// ---------------- T1 v5: G tile in LDS, X + G both 1-deep prefetched -------
// T1[br][o][b][m][cl] = sum_n G[br][o][n][m] * X[br][b][n][cl]
// Round-17 ledger put t1 at ~27 us (~2.4x its ~11 us issue floor): the two
// wave-uniform G float4 VMEM loads per n were consumed immediately (X was
// prefetched, G was not). Stage the 2 KB G tile in LDS once; prefetch both
// X (global) and G row (LDS broadcast) one n ahead. Same fma order.
__global__ __launch_bounds__(256, 3) void k_t1(
    const float* __restrict__ X, const float* __restrict__ G,
    short* __restrict__ T1hi, short* __restrict__ T1lo)
{
    __shared__ float gs[64][8];   // 2 KB
    const int tid = threadIdx.x;
    const int o = blockIdx.y >> 3, b = blockIdx.y & 7;
    const int br = blockIdx.z >> 3, m0 = (blockIdx.z & 7) * 8;
    const int cl0 = blockIdx.x * 2048 + tid * 8;
    const size_t xb = (size_t)(br * 8 + b) * 262144 + cl0;
    const float* gp = G + (size_t)(br * 3 + o) * 4096 + m0;

    // stage G tile: gs[n][j] = G[br][o][n][m0+j]
#pragma unroll
    for (int i = tid; i < 512; i += 256)
        gs[i >> 3][i & 7] = gp[(i >> 3) * 64 + (i & 7)];
    __syncthreads();

    float acc[8][8];   // [mm][c]
#pragma unroll
    for (int mm = 0; mm < 8; ++mm)
#pragma unroll
        for (int c = 0; c < 8; ++c) acc[mm][c] = 0.f;

    float4 nx0 = *(const float4*)(X + xb);       // prefetch n=0
    float4 nx1 = *(const float4*)(X + xb + 4);
    float4 ng0 = *(const float4*)&gs[0][0];
    float4 ng1 = *(const float4*)&gs[0][4];

#pragma unroll 2
    for (int n = 0; n < 64; ++n) {
        float4 x0 = nx0, x1 = nx1;
        float4 g0 = ng0, g1 = ng1;
        if (n < 63) {   // issue n+1's operands; latency hides under n's fma
            nx0 = *(const float4*)(X + xb + (size_t)(n + 1) * 4096);
            nx1 = *(const float4*)(X + xb + (size_t)(n + 1) * 4096 + 4);
            ng0 = *(const float4*)&gs[n + 1][0];
            ng1 = *(const float4*)&gs[n + 1][4];
        }
        float xf[8] = {x0.x, x0.y, x0.z, x0.w, x1.x, x1.y, x1.z, x1.w};
        float gv[8] = {g0.x, g0.y, g0.z, g0.w, g1.x, g1.y, g1.z, g1.w};
#pragma unroll
        for (int mm = 0; mm < 8; ++mm) {
            float g = gv[mm];
#pragma unroll
            for (int c = 0; c < 8; ++c)
                acc[mm][c] = fmaf(xf[c], g, acc[mm][c]);
        }
    }
    const size_t tb = ((size_t)(br * 3 + o) * 8 + b) * 262144 + cl0;
#pragma unroll
    for (int mm = 0; mm < 8; ++mm) {
        short8 h8, l8;
#pragma unroll
        for (int c = 0; c < 8; ++c) {
            float f = acc[mm][c];
            short hi = bf16_cvt(f);
            h8[c] = hi;
            l8[c] = bf16_cvt(f - bf16_tof(hi));
        }
        *(short8*)(T1hi + tb + (size_t)(m0 + mm) * 4096) = h8;
        *(short8*)(T1lo + tb + (size_t)(m0 + mm) * 4096) = l8;
    }
}

// ---------------- T2 + FC (MFMA), LDS-staged T1, wave-split W --------------
// Per (br,b,m): U[d][c][h] = sum_{o,l} T1[o][c][l] W[(o,d)l][h]   (phase 1)
//              out[e][h]  = bias[h] + sum_{d,c} G[d][c][e] U[d][c][h] (ph 2)
// U layout: round-8 72-pad. LDS 55296 B. Layer-1 output plain f32.
__global__ __launch_bounds__(256, 3) void k_t2fc(
    const short* __restrict__ T1hi, const short* __restrict__ T1lo,
    const short* __restrict__ Wfhi, const short* __restrict__ Wflo,
    const short* __restrict__ Gfhi, const short* __restrict__ Gflo,
    const float* __restrict__ bias, const float* __restrict__ fcW,
    const float* __restrict__ fcb,
    float* __restrict__ Yout, float* __restrict__ yws, int last)
{
    // region reuse: stage T1 [6][4096] (24576 sh) -> U [2][3][64][72] (27648)
    __shared__ __align__(16) short lds[27648];
    const int tid = threadIdx.x, lane = tid & 63;
    const int r16 = lane & 15, q = lane >> 4;
    const int w = __builtin_amdgcn_readfirstlane(tid >> 6);
    const int m = blockIdx.x, b = blockIdx.y, br = blockIdx.z;

    // ---- stage T1 slice (3 o x 2 plane x 4096) into LDS, XOR-swizzled ----
    const size_t t1b = (((size_t)br * 24 + b) * 64 + m) * 4096;
#pragma unroll
    for (int it = 0; it < 12; ++it) {
        int flat = it * 2048 + tid * 8;
        int p2 = flat >> 12;            // o*2 + plane
        int li = flat & 4095;           // c*64 + l
        int c = li >> 6, l = li & 63;
        const short* src = ((p2 & 1) ? T1lo : T1hi) + t1b +
                           (size_t)(p2 >> 1) * 2097152 + li;
        int dst = p2 * 4096 + c * 64 + (l ^ ((c & 7) << 3));
        *(short8*)&lds[dst] = *(const short8*)src;
    }
    __syncthreads();

    // ---- phase 1: U = T1 @ W. Wave w owns combos {w*3..w*3+2} (d*4+ht),
    //      all 4 c-tiles. W-frag loads: 36/wave (no cross-wave redundancy).
    f32x4 acc1[3][4];   // [i][ct]
#pragma unroll
    for (int i = 0; i < 3; ++i)
#pragma unroll
        for (int ct = 0; ct < 4; ++ct)
#pragma unroll
            for (int r = 0; r < 4; ++r) acc1[i][ct][r] = 0.f;

#pragma unroll
    for (int kk = 0; kk < 6; ++kk) {
        const int o = kk >> 1;
        short8 Wh[3], Wl[3];
#pragma unroll
        for (int i = 0; i < 3; ++i) {
            const int combo = w * 3 + i;          // d*4 + ht
            const int d = combo >> 2, ht = combo & 3;
            const int widx = ((((br * 3 + d) * 4 + ht) * 6 + kk) << 9) + lane * 8;
            Wh[i] = *(const short8*)(Wfhi + widx);
            Wl[i] = *(const short8*)(Wflo + widx);
        }
        short8 Ah[4], Al[4];
#pragma unroll
        for (int ct = 0; ct < 4; ++ct) {
            const int c = ct * 16 + r16;
            const int lbase = ((kk & 1) * 32 + q * 8) ^ ((r16 & 7) << 3);
            Ah[ct] = *(const short8*)&lds[(o * 2 + 0) * 4096 + c * 64 + lbase];
            Al[ct] = *(const short8*)&lds[(o * 2 + 1) * 4096 + c * 64 + lbase];
        }
#pragma unroll
        for (int i = 0; i < 3; ++i)
#pragma unroll
            for (int ct = 0; ct < 4; ++ct) {
                acc1[i][ct] = __builtin_amdgcn_mfma_f32_16x16x32_bf16(
                    Ah[ct], Wh[i], acc1[i][ct], 0, 0, 0);
                acc1[i][ct] = __builtin_amdgcn_mfma_f32_16x16x32_bf16(
                    Ah[ct], Wl[i], acc1[i][ct], 0, 0, 0);
                acc1[i][ct] = __builtin_amdgcn_mfma_f32_16x16x32_bf16(
                    Al[ct], Wh[i], acc1[i][ct], 0, 0, 0);
            }
    }
    __syncthreads();   // T1-LDS reads done; region becomes U

    short* u0 = lds;
    short* u1 = lds + 13824;   // 3*64*72
#pragma unroll
    for (int i = 0; i < 3; ++i) {
        const int combo = w * 3 + i;
        const int d = combo >> 2, ht = combo & 3;
        const int h = ht * 16 + r16;
#pragma unroll
        for (int ct = 0; ct < 4; ++ct)
#pragma unroll
            for (int r = 0; r < 4; ++r) {
                float f = acc1[i][ct][r];
                int c = ct * 16 + q * 4 + r;
                int ui = (d * 64 + h) * 72 + c;
                short hi = bf16_cvt(f);
                u0[ui] = hi;
                u1[ui] = bf16_cvt(f - bf16_tof(hi));
            }
    }
    __syncthreads();

    // ---- phase 2: out = G^T @ U + bias (wave w owns e-tile w)
    f32x4 acc2[4];
#pragma unroll
    for (int ht = 0; ht < 4; ++ht) {
        float bb = bias[br * 64 + ht * 16 + r16];
#pragma unroll
        for (int r = 0; r < 4; ++r) acc2[ht][r] = bb;
    }
#pragma unroll
    for (int kk = 0; kk < 6; ++kk) {
        const int gi = (((br * 4 + w) * 6 + kk) << 9) + lane * 8;
        short8 A2h = *(const short8*)(Gfhi + gi);
        short8 A2l = *(const short8*)(Gflo + gi);
        const int d = kk >> 1, cb = (kk & 1) * 32 + q * 8;
#pragma unroll
        for (int ht = 0; ht < 4; ++ht) {
            const int bi = (d * 64 + ht * 16 + r16) * 72 + cb;
            short8 B2h = *(const short8*)(u0 + bi);
            short8 B2l = *(const short8*)(u1 + bi);
            acc2[ht] = __builtin_amdgcn_mfma_f32_16x16x32_bf16(
                A2h, B2h, acc2[ht], 0, 0, 0);
            acc2[ht] = __builtin_amdgcn_mfma_f32_16x16x32_bf16(
                A2h, B2l, acc2[ht], 0, 0, 0);
            acc2[ht] = __builtin_amdgcn_mfma_f32_16x16x32_bf16(
                A2l, B2h, acc2[ht], 0, 0, 0);
        }
    }

    if (!last) {
        __syncthreads();
        float* ldsO = (float*)lds;   // 16 KB
#pragma unroll
        for (int ht = 0; ht < 4; ++ht)
#pragma unroll
            for (int r = 0; r < 4; ++r)
                ldsO[(w * 16 + q * 4 + r) * 64 + ht * 16 + r16] = acc2[ht][r];
        __syncthreads();
        const size_t yb = ((size_t)(br * 8 + b) * 64 + m) * 4096;
        const int i0 = tid * 16;
#pragma unroll
        for (int k4 = 0; k4 < 4; ++k4)
            *(float4*)(Yout + yb + i0 + k4 * 4) =
                *(const float4*)(ldsO + i0 + k4 * 4);
    } else {
        float p[4];
#pragma unroll
        for (int r = 0; r < 4; ++r) {
            p[r] = 0.f;
#pragma unroll
            for (int ht = 0; ht < 4; ++ht)
                p[r] += acc2[ht][r] * fcW[br * 64 + ht * 16 + r16];
        }
#pragma unroll
        for (int off = 1; off < 16; off <<= 1)
#pragma unroll
            for (int r = 0; r < 4; ++r) p[r] += __shfl_xor(p[r], off);
        if (r16 == 0) {
            float fb = fcb[br];
#pragma unroll
            for (int r = 0; r < 4; ++r) {
                int e = w * 16 + q * 4 + r;
                yws[(size_t)br * 32768 + (size_t)b * 4096 + m * 64 + e] =
                    fmaxf(p[r] + fb, 0.f);
            }
        }
    }
}

__global__ __launch_bounds__(256) void k_mean(
    const float* __restrict__ yws, float* __restrict__ out)
{
    int idx = blockIdx.x * 256 + threadIdx.x;
    out[idx] = 0.5f * (yws[idx] + yws[32768 + idx]);
}

extern "C" void kernel_launch(void* const* d_in, const int* in_sizes, int n_in,
                              void* d_out, int out_size, void* d_ws, size_t ws_size,
                              hipStream_t stream)
{
    const float* x   = (const float*)d_in[0];
    const float* G   = (const float*)d_in[1];
    const float* wih = (const float*)d_in[2];
    const float* whh = (const float*)d_in[3];
    const float* bih = (const float*)d_in[4];
    const float* bhh = (const float*)d_in[5];
    const float* W0  = (const float*)d_in[6];
    const float* b0  = (const float*)d_in[7];
    const float* W1  = (const float*)d_in[8];
    const float* b1  = (const float*)d_in[9];
    const float* fcW = (const float*)d_in[10];
    const float* fcb = (const float*)d_in[11];
    float* out = (float*)d_out;

    // ws layout. X32/Y1 are f32 (same bytes as the old hi+lo pair).
    float* X32  = (float*)d_ws;             // 4,194,304 f32 (16.8 MB)
    short* T1hi = (short*)(X32 + 4194304);  // 12,582,912 shorts
    short* T1lo = T1hi + 12582912;
    float* yws  = (float*)(T1lo + 12582912);   // 65,536 f32
    short* Wfhi = (short*)(yws + 65536);    // 147,456
    short* Wflo = Wfhi + 147456;
    short* Gfhi = Wflo + 147456;            // 24,576
    short* Gflo = Gfhi + 24576;
    short* Whfhi = Gflo + 24576;            // 32,768
    short* Whflo = Whfhi + 32768;
    float* Y1   = X32;                      // reuse (X dead after layer-1 t1)

    k_prep<<<800, 256, 0, stream>>>(G, W0, W1, whh,
                                    Wfhi, Wflo, Gfhi, Gflo, Whfhi, Whflo);
    k_lstm<<<dim3(2048, 2), 256, 0, stream>>>(x, Whfhi, Whflo, wih, bih, bhh,
                                              X32);

    // layer 1
    k_t1<<<dim3(2, 24, 16), 256, 0, stream>>>(X32, G, T1hi, T1lo);
    k_t2fc<<<dim3(64, 8, 2), 256, 0, stream>>>(T1hi, T1lo, Wfhi, Wflo,
                                               Gfhi, Gflo, b0, fcW, fcb,
                                               Y1, yws, 0);
    // layer 2
    k_t1<<<dim3(2, 24, 16), 256, 0, stream>>>(Y1, G, T1hi, T1lo);
    k_t2fc<<<dim3(64, 8, 2), 256, 0, stream>>>(T1hi, T1lo,
                                               Wfhi + 73728, Wflo + 73728,
                                               Gfhi, Gflo, b1, fcW, fcb,
                                               (float*)nullptr, yws, 1);
    k_mean<<<128, 256, 0, stream>>>(yws, out);
}

// Round 19
// 205.113 us; speedup vs baseline: 1.0344x; 1.0344x over previous
//
#include <hip/hip_runtime.h>
#include <hip/hip_bf16.h>

// M=2 branches, K=3 diffusion, N=64, I=1, H=64, B=8, T=12

typedef __attribute__((ext_vector_type(8))) short short8;   // 8 bf16 (4 VGPRs)
typedef __attribute__((ext_vector_type(4))) float f32x4;    // 4 fp32

__device__ __forceinline__ short bf16_cvt(float f) {       // RNE, 1-2 ops
    __hip_bfloat16 h = __float2bfloat16(f);
    return __builtin_bit_cast(short, h);
}
__device__ __forceinline__ float bf16_tof(short s) {
    union { unsigned u; float f; } v; v.u = ((unsigned)s) << 16;
    return v.f;
}

// ---------------- prep: pack W, G^T, Whh into MFMA fragment order ----------
// Wf [layer][br][d][ht][kk][lane][8] : 147456/plane
// Gf [br][et][kk][lane][8]           : 24576/plane
// Whf[br][kt][gg][w][lane][8]        : 32768/plane  (B[k][gate] of WhhT)
__global__ __launch_bounds__(256) void k_prep(
    const float* __restrict__ G, const float* __restrict__ W0,
    const float* __restrict__ W1, const float* __restrict__ whh,
    short* __restrict__ Wfhi, short* __restrict__ Wflo,
    short* __restrict__ Gfhi, short* __restrict__ Gflo,
    short* __restrict__ Whfhi, short* __restrict__ Whflo)
{
    int idx = blockIdx.x * 256 + threadIdx.x;
    float v; short *dh, *dl; int didx;
    if (idx < 147456) {
        int j = idx & 7, lane = (idx >> 3) & 63, kk = (idx >> 9) % 6;
        int t2 = idx / 3072;
        int ht = t2 & 3; t2 >>= 2;
        int d = t2 % 3; t2 /= 3;
        int br = t2 & 1, layer = t2 >> 1;
        int k = kk * 32 + ((lane >> 4) << 3) + j;
        int o = k >> 6, l = k & 63, h = ht * 16 + (lane & 15);
        const float* Wp = layer ? W1 : W0;
        v = Wp[((size_t)br * 576 + (o * 3 + d) * 64 + l) * 64 + h];
        dh = Wfhi; dl = Wflo; didx = idx;
    } else if (idx < 172032) {
        int i2 = idx - 147456;
        int j = i2 & 7, lane = (i2 >> 3) & 63, kk = (i2 >> 9) % 6;
        int t2 = i2 / 3072;
        int et = t2 & 3, br = t2 >> 2;
        int k = kk * 32 + ((lane >> 4) << 3) + j;
        int d = k >> 6, c = k & 63, e = et * 16 + (lane & 15);
        v = G[(((size_t)br * 3 + d) * 64 + c) * 64 + e];
        dh = Gfhi; dl = Gflo; didx = i2;
    } else {
        int i3 = idx - 172032;
        int j = i3 & 7, lane = (i3 >> 3) & 63;
        int w = (i3 >> 9) & 3, gg = (i3 >> 11) & 3;
        int kt = (i3 >> 13) & 1, br = (i3 >> 14) & 1;
        int gate = gg * 64 + w * 16 + (lane & 15);
        int k = kt * 32 + ((lane >> 4) << 3) + j;
        v = whh[((size_t)br * 256 + gate) * 64 + k];
        dh = Whfhi; dl = Whflo; didx = i3;
    }
    short hi = bf16_cvt(v);
    dh[didx] = hi;
    dl[didx] = bf16_cvt(v - bf16_tof(hi));
}

// ---------------- LSTM v4.3: register weights, x prefetch, (256,3) ---------
// f32 X output. Plateaued at ~97.5 us, VALU+Mfma ~98% issue-saturated.
__global__ __launch_bounds__(256, 3) void k_lstm(
    const float* __restrict__ x, const short* __restrict__ Whfhi,
    const short* __restrict__ Whflo, const float* __restrict__ wih,
    const float* __restrict__ bih, const float* __restrict__ bhh,
    float* __restrict__ Xout)
{
    __shared__ short hbuf[2][2][16][64];   // [dbuf][plane][seq][hid^swz] 8 KB
    const int tid = threadIdx.x;
    const int lane = tid & 63;
    const int w = __builtin_amdgcn_readfirstlane(tid >> 6);   // gate slice 0..3
    const int q = lane >> 4, r16 = lane & 15;
    const int br = blockIdx.y;
    const int bx = blockIdx.x;
    const int dg = bx & 3, o = (bx >> 2) & 63, b = bx >> 8;

    // weight-stationary B fragments (hi/lo), statically indexed -> registers
    short8 Bh[2][4], Bl[2][4];
    {
        const short* wbh = Whfhi + (size_t)br * 16384;
        const short* wbl = Whflo + (size_t)br * 16384;
#pragma unroll
        for (int kt = 0; kt < 2; ++kt)
#pragma unroll
            for (int gg = 0; gg < 4; ++gg) {
                const int bidx = (((kt * 4 + gg) * 4 + w) * 64 + lane) * 8;
                Bh[kt][gg] = *(const short8*)(wbh + bidx);
                Bl[kt][gg] = *(const short8*)(wbl + bidx);
            }
    }

    float wihv[4], biasv[4];
#pragma unroll
    for (int gg = 0; gg < 4; ++gg) {
        const int gate = gg * 64 + w * 16 + r16;
        wihv[gg] = wih[br * 256 + gate];
        biasv[gg] = bih[br * 256 + gate] + bhh[br * 256 + gate];
    }

    float cst[4] = {0.f, 0.f, 0.f, 0.f};
    const float* xb = x + (size_t)b * 12 * 4096 + o * 64 + dg * 16;
    const size_t hob = ((size_t)(br * 8 + b) * 64 + o) * 4096 + dg * 1024;
    const int hid = w * 16 + r16;

    const float L2E = 1.442695041f, L2E2 = 2.885390082f;

    float4 nx = *(const float4*)(xb + q * 4);   // prefetch t=0

    for (int t = 0; t < 12; ++t) {
        float4 xv = nx;
        if (t < 11)   // issue next step's x early; hides under MFMA+acts
            nx = *(const float4*)(xb + (size_t)(t + 1) * 4096 + q * 4);
        float xm[4] = {xv.x, xv.y, xv.z, xv.w};
        f32x4 acc[4];   // [gg]
#pragma unroll
        for (int r = 0; r < 4; ++r)
#pragma unroll
            for (int gg = 0; gg < 4; ++gg)
                acc[gg][r] = fmaf(xm[r], wihv[gg], biasv[gg]);

        if (t > 0) {
            const short* hb0 = &hbuf[t & 1][0][0][0];
#pragma unroll
            for (int kt = 0; kt < 2; ++kt) {
                const int col = (kt * 32 + q * 8) ^ ((r16 & 7) << 3);
                short8 Ah = *(const short8*)&hb0[r16 * 64 + col];
                short8 Al = *(const short8*)&hb0[1024 + r16 * 64 + col];
#pragma unroll
                for (int gg = 0; gg < 4; ++gg) {
                    acc[gg] = __builtin_amdgcn_mfma_f32_16x16x32_bf16(
                        Ah, Bh[kt][gg], acc[gg], 0, 0, 0);
                    acc[gg] = __builtin_amdgcn_mfma_f32_16x16x32_bf16(
                        Ah, Bl[kt][gg], acc[gg], 0, 0, 0);
                    acc[gg] = __builtin_amdgcn_mfma_f32_16x16x32_bf16(
                        Al, Bh[kt][gg], acc[gg], 0, 0, 0);
                }
            }
        }
        // activations, torch order i,f,g,o. Fused products share one rcp.
        float hv_[4];
#pragma unroll
        for (int r = 0; r < 4; ++r) {
            float ei = __builtin_amdgcn_exp2f(acc[0][r] * -L2E);
            float Eg = __builtin_amdgcn_exp2f(acc[2][r] * L2E2);
            float ef = __builtin_amdgcn_exp2f(acc[1][r] * -L2E);
            float igt = (Eg - 1.f) *
                        __builtin_amdgcn_rcpf((1.f + ei) * (Eg + 1.f));
            float fg = __builtin_amdgcn_rcpf(1.f + ef);
            float c = fmaf(fg, cst[r], igt);
            cst[r] = c;
            float eo = __builtin_amdgcn_exp2f(acc[3][r] * -L2E);
            float Ec = __builtin_amdgcn_exp2f(c * L2E2);
            hv_[r] = (Ec - 1.f) *
                     __builtin_amdgcn_rcpf((1.f + eo) * (Ec + 1.f));
        }
        if (t == 11) {
#pragma unroll
            for (int r = 0; r < 4; ++r) {
                int seq = q * 4 + r;
                Xout[hob + seq * 64 + hid] = hv_[r];
            }
        } else {
            short* hw0 = &hbuf[(t + 1) & 1][0][0][0];
#pragma unroll
            for (int r = 0; r < 4; ++r) {
                int seq = q * 4 + r;
                int col = hid ^ ((seq & 7) << 3);
                short hi = bf16_cvt(hv_[r]);
                hw0[seq * 64 + col] = hi;
                hw0[1024 + seq * 64 + col] = bf16_cvt(hv_[r] - bf16_tof(hi));
            }
            __syncthreads();   // single barrier per step (dbuf)
        }
    }
}

// ---------------- T1 v6: 2-deep software pipeline for X and G --------------
// T1[br][o][b][m][cl] = sum_n G[br][o][n][m] * X[br][b][n][cl]
// v5's LDS-G regressed (G was already L1-hot; barrier cost). Real gap: the
// 1-deep prefetch covers ~136 cyc but load latency is ~200-400 -> every 2nd
// iter stalls. 2-deep pipeline (even/odd named slots, explicit 2-step body)
// issues loads 2 iterations ahead (~280 cyc cover). Same fma order over n.
__global__ __launch_bounds__(256, 3) void k_t1(
    const float* __restrict__ X, const float* __restrict__ G,
    short* __restrict__ T1hi, short* __restrict__ T1lo)
{
    const int o = blockIdx.y >> 3, b = blockIdx.y & 7;
    const int br = blockIdx.z >> 3, m0 = (blockIdx.z & 7) * 8;
    const int cl0 = blockIdx.x * 2048 + threadIdx.x * 8;
    const size_t xb = (size_t)(br * 8 + b) * 262144 + cl0;
    const float* gp = G + (size_t)(br * 3 + o) * 4096 + m0;

    float acc[8][8];   // [mm][c]
#pragma unroll
    for (int mm = 0; mm < 8; ++mm)
#pragma unroll
        for (int c = 0; c < 8; ++c) acc[mm][c] = 0.f;

    // 2-deep pipeline: slot A = even n, slot B = odd n (named regs, rule 20)
    float4 ax0 = *(const float4*)(X + xb);
    float4 ax1 = *(const float4*)(X + xb + 4);
    float4 ag0 = *(const float4*)(gp);
    float4 ag1 = *(const float4*)(gp + 4);
    float4 bx0 = *(const float4*)(X + xb + 4096);
    float4 bx1 = *(const float4*)(X + xb + 4096 + 4);
    float4 bg0 = *(const float4*)(gp + 64);
    float4 bg1 = *(const float4*)(gp + 68);

#pragma unroll 2
    for (int nn = 0; nn < 32; ++nn) {
        const int n0 = 2 * nn;
        // ---- even iteration n0: consume slot A, refill with n0+2
        float4 cx0 = ax0, cx1 = ax1, cg0 = ag0, cg1 = ag1;
        if (n0 + 2 < 64) {
            ax0 = *(const float4*)(X + xb + (size_t)(n0 + 2) * 4096);
            ax1 = *(const float4*)(X + xb + (size_t)(n0 + 2) * 4096 + 4);
            ag0 = *(const float4*)(gp + (n0 + 2) * 64);
            ag1 = *(const float4*)(gp + (n0 + 2) * 64 + 4);
        }
        {
            float xf[8] = {cx0.x, cx0.y, cx0.z, cx0.w,
                           cx1.x, cx1.y, cx1.z, cx1.w};
            float gv[8] = {cg0.x, cg0.y, cg0.z, cg0.w,
                           cg1.x, cg1.y, cg1.z, cg1.w};
#pragma unroll
            for (int mm = 0; mm < 8; ++mm) {
                float g = gv[mm];
#pragma unroll
                for (int c = 0; c < 8; ++c)
                    acc[mm][c] = fmaf(xf[c], g, acc[mm][c]);
            }
        }
        // ---- odd iteration n0+1: consume slot B, refill with n0+3
        float4 dx0 = bx0, dx1 = bx1, dg0 = bg0, dg1 = bg1;
        if (n0 + 3 < 64) {
            bx0 = *(const float4*)(X + xb + (size_t)(n0 + 3) * 4096);
            bx1 = *(const float4*)(X + xb + (size_t)(n0 + 3) * 4096 + 4);
            bg0 = *(const float4*)(gp + (n0 + 3) * 64);
            bg1 = *(const float4*)(gp + (n0 + 3) * 64 + 4);
        }
        {
            float xf[8] = {dx0.x, dx0.y, dx0.z, dx0.w,
                           dx1.x, dx1.y, dx1.z, dx1.w};
            float gv[8] = {dg0.x, dg0.y, dg0.z, dg0.w,
                           dg1.x, dg1.y, dg1.z, dg1.w};
#pragma unroll
            for (int mm = 0; mm < 8; ++mm) {
                float g = gv[mm];
#pragma unroll
                for (int c = 0; c < 8; ++c)
                    acc[mm][c] = fmaf(xf[c], g, acc[mm][c]);
            }
        }
    }
    const size_t tb = ((size_t)(br * 3 + o) * 8 + b) * 262144 + cl0;
#pragma unroll
    for (int mm = 0; mm < 8; ++mm) {
        short8 h8, l8;
#pragma unroll
        for (int c = 0; c < 8; ++c) {
            float f = acc[mm][c];
            short hi = bf16_cvt(f);
            h8[c] = hi;
            l8[c] = bf16_cvt(f - bf16_tof(hi));
        }
        *(short8*)(T1hi + tb + (size_t)(m0 + mm) * 4096) = h8;
        *(short8*)(T1lo + tb + (size_t)(m0 + mm) * 4096) = l8;
    }
}

// ---------------- T2 + FC (MFMA), LDS-staged T1, wave-split W --------------
// Per (br,b,m): U[d][c][h] = sum_{o,l} T1[o][c][l] W[(o,d)l][h]   (phase 1)
//              out[e][h]  = bias[h] + sum_{d,c} G[d][c][e] U[d][c][h] (ph 2)
// U layout: round-8 72-pad. LDS 55296 B. Layer-1 output plain f32.
__global__ __launch_bounds__(256, 3) void k_t2fc(
    const short* __restrict__ T1hi, const short* __restrict__ T1lo,
    const short* __restrict__ Wfhi, const short* __restrict__ Wflo,
    const short* __restrict__ Gfhi, const short* __restrict__ Gflo,
    const float* __restrict__ bias, const float* __restrict__ fcW,
    const float* __restrict__ fcb,
    float* __restrict__ Yout, float* __restrict__ yws, int last)
{
    // region reuse: stage T1 [6][4096] (24576 sh) -> U [2][3][64][72] (27648)
    __shared__ __align__(16) short lds[27648];
    const int tid = threadIdx.x, lane = tid & 63;
    const int r16 = lane & 15, q = lane >> 4;
    const int w = __builtin_amdgcn_readfirstlane(tid >> 6);
    const int m = blockIdx.x, b = blockIdx.y, br = blockIdx.z;

    // ---- stage T1 slice (3 o x 2 plane x 4096) into LDS, XOR-swizzled ----
    const size_t t1b = (((size_t)br * 24 + b) * 64 + m) * 4096;
#pragma unroll
    for (int it = 0; it < 12; ++it) {
        int flat = it * 2048 + tid * 8;
        int p2 = flat >> 12;            // o*2 + plane
        int li = flat & 4095;           // c*64 + l
        int c = li >> 6, l = li & 63;
        const short* src = ((p2 & 1) ? T1lo : T1hi) + t1b +
                           (size_t)(p2 >> 1) * 2097152 + li;
        int dst = p2 * 4096 + c * 64 + (l ^ ((c & 7) << 3));
        *(short8*)&lds[dst] = *(const short8*)src;
    }
    __syncthreads();

    // ---- phase 1: U = T1 @ W. Wave w owns combos {w*3..w*3+2} (d*4+ht),
    //      all 4 c-tiles. W-frag loads: 36/wave (no cross-wave redundancy).
    f32x4 acc1[3][4];   // [i][ct]
#pragma unroll
    for (int i = 0; i < 3; ++i)
#pragma unroll
        for (int ct = 0; ct < 4; ++ct)
#pragma unroll
            for (int r = 0; r < 4; ++r) acc1[i][ct][r] = 0.f;

#pragma unroll
    for (int kk = 0; kk < 6; ++kk) {
        const int o = kk >> 1;
        short8 Wh[3], Wl[3];
#pragma unroll
        for (int i = 0; i < 3; ++i) {
            const int combo = w * 3 + i;          // d*4 + ht
            const int d = combo >> 2, ht = combo & 3;
            const int widx = ((((br * 3 + d) * 4 + ht) * 6 + kk) << 9) + lane * 8;
            Wh[i] = *(const short8*)(Wfhi + widx);
            Wl[i] = *(const short8*)(Wflo + widx);
        }
        short8 Ah[4], Al[4];
#pragma unroll
        for (int ct = 0; ct < 4; ++ct) {
            const int c = ct * 16 + r16;
            const int lbase = ((kk & 1) * 32 + q * 8) ^ ((r16 & 7) << 3);
            Ah[ct] = *(const short8*)&lds[(o * 2 + 0) * 4096 + c * 64 + lbase];
            Al[ct] = *(const short8*)&lds[(o * 2 + 1) * 4096 + c * 64 + lbase];
        }
#pragma unroll
        for (int i = 0; i < 3; ++i)
#pragma unroll
            for (int ct = 0; ct < 4; ++ct) {
                acc1[i][ct] = __builtin_amdgcn_mfma_f32_16x16x32_bf16(
                    Ah[ct], Wh[i], acc1[i][ct], 0, 0, 0);
                acc1[i][ct] = __builtin_amdgcn_mfma_f32_16x16x32_bf16(
                    Ah[ct], Wl[i], acc1[i][ct], 0, 0, 0);
                acc1[i][ct] = __builtin_amdgcn_mfma_f32_16x16x32_bf16(
                    Al[ct], Wh[i], acc1[i][ct], 0, 0, 0);
            }
    }
    __syncthreads();   // T1-LDS reads done; region becomes U

    short* u0 = lds;
    short* u1 = lds + 13824;   // 3*64*72
#pragma unroll
    for (int i = 0; i < 3; ++i) {
        const int combo = w * 3 + i;
        const int d = combo >> 2, ht = combo & 3;
        const int h = ht * 16 + r16;
#pragma unroll
        for (int ct = 0; ct < 4; ++ct)
#pragma unroll
            for (int r = 0; r < 4; ++r) {
                float f = acc1[i][ct][r];
                int c = ct * 16 + q * 4 + r;
                int ui = (d * 64 + h) * 72 + c;
                short hi = bf16_cvt(f);
                u0[ui] = hi;
                u1[ui] = bf16_cvt(f - bf16_tof(hi));
            }
    }
    __syncthreads();

    // ---- phase 2: out = G^T @ U + bias (wave w owns e-tile w)
    f32x4 acc2[4];
#pragma unroll
    for (int ht = 0; ht < 4; ++ht) {
        float bb = bias[br * 64 + ht * 16 + r16];
#pragma unroll
        for (int r = 0; r < 4; ++r) acc2[ht][r] = bb;
    }
#pragma unroll
    for (int kk = 0; kk < 6; ++kk) {
        const int gi = (((br * 4 + w) * 6 + kk) << 9) + lane * 8;
        short8 A2h = *(const short8*)(Gfhi + gi);
        short8 A2l = *(const short8*)(Gflo + gi);
        const int d = kk >> 1, cb = (kk & 1) * 32 + q * 8;
#pragma unroll
        for (int ht = 0; ht < 4; ++ht) {
            const int bi = (d * 64 + ht * 16 + r16) * 72 + cb;
            short8 B2h = *(const short8*)(u0 + bi);
            short8 B2l = *(const short8*)(u1 + bi);
            acc2[ht] = __builtin_amdgcn_mfma_f32_16x16x32_bf16(
                A2h, B2h, acc2[ht], 0, 0, 0);
            acc2[ht] = __builtin_amdgcn_mfma_f32_16x16x32_bf16(
                A2h, B2l, acc2[ht], 0, 0, 0);
            acc2[ht] = __builtin_amdgcn_mfma_f32_16x16x32_bf16(
                A2l, B2h, acc2[ht], 0, 0, 0);
        }
    }

    if (!last) {
        __syncthreads();
        float* ldsO = (float*)lds;   // 16 KB
#pragma unroll
        for (int ht = 0; ht < 4; ++ht)
#pragma unroll
            for (int r = 0; r < 4; ++r)
                ldsO[(w * 16 + q * 4 + r) * 64 + ht * 16 + r16] = acc2[ht][r];
        __syncthreads();
        const size_t yb = ((size_t)(br * 8 + b) * 64 + m) * 4096;
        const int i0 = tid * 16;
#pragma unroll
        for (int k4 = 0; k4 < 4; ++k4)
            *(float4*)(Yout + yb + i0 + k4 * 4) =
                *(const float4*)(ldsO + i0 + k4 * 4);
    } else {
        float p[4];
#pragma unroll
        for (int r = 0; r < 4; ++r) {
            p[r] = 0.f;
#pragma unroll
            for (int ht = 0; ht < 4; ++ht)
                p[r] += acc2[ht][r] * fcW[br * 64 + ht * 16 + r16];
        }
#pragma unroll
        for (int off = 1; off < 16; off <<= 1)
#pragma unroll
            for (int r = 0; r < 4; ++r) p[r] += __shfl_xor(p[r], off);
        if (r16 == 0) {
            float fb = fcb[br];
#pragma unroll
            for (int r = 0; r < 4; ++r) {
                int e = w * 16 + q * 4 + r;
                yws[(size_t)br * 32768 + (size_t)b * 4096 + m * 64 + e] =
                    fmaxf(p[r] + fb, 0.f);
            }
        }
    }
}

__global__ __launch_bounds__(256) void k_mean(
    const float* __restrict__ yws, float* __restrict__ out)
{
    int idx = blockIdx.x * 256 + threadIdx.x;
    out[idx] = 0.5f * (yws[idx] + yws[32768 + idx]);
}

extern "C" void kernel_launch(void* const* d_in, const int* in_sizes, int n_in,
                              void* d_out, int out_size, void* d_ws, size_t ws_size,
                              hipStream_t stream)
{
    const float* x   = (const float*)d_in[0];
    const float* G   = (const float*)d_in[1];
    const float* wih = (const float*)d_in[2];
    const float* whh = (const float*)d_in[3];
    const float* bih = (const float*)d_in[4];
    const float* bhh = (const float*)d_in[5];
    const float* W0  = (const float*)d_in[6];
    const float* b0  = (const float*)d_in[7];
    const float* W1  = (const float*)d_in[8];
    const float* b1  = (const float*)d_in[9];
    const float* fcW = (const float*)d_in[10];
    const float* fcb = (const float*)d_in[11];
    float* out = (float*)d_out;

    // ws layout. X32/Y1 are f32 (same bytes as the old hi+lo pair).
    float* X32  = (float*)d_ws;             // 4,194,304 f32 (16.8 MB)
    short* T1hi = (short*)(X32 + 4194304);  // 12,582,912 shorts
    short* T1lo = T1hi + 12582912;
    float* yws  = (float*)(T1lo + 12582912);   // 65,536 f32
    short* Wfhi = (short*)(yws + 65536);    // 147,456
    short* Wflo = Wfhi + 147456;
    short* Gfhi = Wflo + 147456;            // 24,576
    short* Gflo = Gfhi + 24576;
    short* Whfhi = Gflo + 24576;            // 32,768
    short* Whflo = Whfhi + 32768;
    float* Y1   = X32;                      // reuse (X dead after layer-1 t1)

    k_prep<<<800, 256, 0, stream>>>(G, W0, W1, whh,
                                    Wfhi, Wflo, Gfhi, Gflo, Whfhi, Whflo);
    k_lstm<<<dim3(2048, 2), 256, 0, stream>>>(x, Whfhi, Whflo, wih, bih, bhh,
                                              X32);

    // layer 1
    k_t1<<<dim3(2, 24, 16), 256, 0, stream>>>(X32, G, T1hi, T1lo);
    k_t2fc<<<dim3(64, 8, 2), 256, 0, stream>>>(T1hi, T1lo, Wfhi, Wflo,
                                               Gfhi, Gflo, b0, fcW, fcb,
                                               Y1, yws, 0);
    // layer 2
    k_t1<<<dim3(2, 24, 16), 256, 0, stream>>>(Y1, G, T1hi, T1lo);
    k_t2fc<<<dim3(64, 8, 2), 256, 0, stream>>>(T1hi, T1lo,
                                               Wfhi + 73728, Wflo + 73728,
                                               Gfhi, Gflo, b1, fcW, fcb,
                                               (float*)nullptr, yws, 1);
    k_mean<<<128, 256, 0, stream>>>(yws, out);
}